// Round 9
// baseline (40362.497 us; speedup 1.0000x reference)
//
#include <hip/hip_runtime.h>
#include <stdint.h>

// DSNN bit-exact fp32. Locked-in facts:
//  - Ref is k-ascending single-accumulator fma (absmax 0.0 through R12); any
//    reorder/reprecision flips spikes chaotically. No MFMA (no fp32 MFMA).
//  - Machine model per CU-j (16 waves, reg-limited at 128 regs/wave ->
//    16 waves/CU, occupancy 48%):
//      VALU-pipe floor 128 cyc (pk_fma HALF-RATE 4cyc; R10 busy=149 ✓),
//      TCP 128 (W dwordx2), LDS broadcast ~ 64*bytes/128 + 2 cyc.
//    R10 (2x b128 f32 spikes + 8 pk_fma): LDS 320 -> wall 305. LDS-BOUND.
//    R12 (u16 pack, scalar expand): C-level pair construction -> v_movs ->
//      VALU 274 -> wall 365. Pairs must be produced PAIR-NATIVE.
//    R13: asm cvt_pk_f32_fp8 op_sel:[1,0] doesn't assemble (VOP1 syntax).
//  - R14/R15/R16 (this; R14/R15 benches were infra failures, resubmitted
//    unchanged): __builtin_amdgcn_cvt_pk_f32_fp8(u32, word):
//    fp8 spikes (OCP e4m3: 1.0=0x38 exact) -> ds_read_b64 (8 rows, ~6cyc,
//    LDS 96/CU-j); builtin returns an f32x2 PAIR natively (no movs), word
//    bool selects bytes {0,1}/{2,3}; 8 col-broadcast pk_fma consume pairs.
//    Model: max(VALU ~160, TCP 128, LDS 96) + stall -> predict ~21-24 ms.

typedef __attribute__((ext_vector_type(2))) float f32x2;
typedef __attribute__((ext_vector_type(4))) float f32x4;

#define ALPHA 0.9f
#define BETA 0.85f
#define NSTEPS 127
#define WGT 1024
#define ROWS 32
#define CPAD 36     // x-stage f32 col stride (floats): 32 rows + 4 pad
#define SPB 40      // fp8 spike col stride (BYTES): 32 rows + 8 pad (8B mult)
#define HPAD 516    // h0buf row stride (floats)

// Update forms verbatim (bit-exact-verified vs np reference), bool spike out.
#define LIF_L0(M, H, B) { float _m = BETA * (M) + (H); \
    (B) = (_m - 1.0f) > 0.0f; (M) = (B) ? 0.0f : _m; }
#define LIF_MID(S, M, A, B) { (S) = ALPHA * (S) + (A); \
    float _m = BETA * (M) + (S); (B) = (_m - 1.0f) > 0.0f; \
    (M) = (B) ? 0.0f : _m; }
#define LIF_OUT(S, M, A) { (S) = ALPHA * (S) + (A); (M) = BETA * (M) + (S); }

// fp8 e4m3 (OCP): 1.0 = 0x38, 0.0 = 0x00. Byte k of a col-dword = row 4*dw+k.
#define PK4B(B0, B1, B2, B3) (((B0) ? 0x38u : 0u) | ((B1) ? 0x3800u : 0u) | \
                              (((B2)) ? 0x380000u : 0u) | ((B3) ? 0x38000000u : 0u))

// Row-pair col-broadcast pk_fma block: acc[p][c] = f32x2 over rows (2p,2p+1)
// of col c. src0 = spike row-pair (normal packed), src1 = wv col-broadcast:
//   col-lo: op_sel:[0,0,0] op_sel_hi:[1,0,1]  (both halves read wv.lo)
//   col-hi: op_sel:[0,1,0] op_sel_hi:[1,1,1]  (both halves read wv.hi)
// Each half is an independent IEEE f32 fma -> bit-exact chain per (row,col).
#define PKCOL8(Q0, Q1, Q2, Q3, WV) \
    asm("v_pk_fma_f32 %0, %8, %12, %0 op_sel:[0,0,0] op_sel_hi:[1,0,1]\n\t" \
        "v_pk_fma_f32 %1, %8, %12, %1 op_sel:[0,1,0] op_sel_hi:[1,1,1]\n\t" \
        "v_pk_fma_f32 %2, %9, %12, %2 op_sel:[0,0,0] op_sel_hi:[1,0,1]\n\t" \
        "v_pk_fma_f32 %3, %9, %12, %3 op_sel:[0,1,0] op_sel_hi:[1,1,1]\n\t" \
        "v_pk_fma_f32 %4, %10, %12, %4 op_sel:[0,0,0] op_sel_hi:[1,0,1]\n\t" \
        "v_pk_fma_f32 %5, %10, %12, %5 op_sel:[0,1,0] op_sel_hi:[1,1,1]\n\t" \
        "v_pk_fma_f32 %6, %11, %12, %6 op_sel:[0,0,0] op_sel_hi:[1,0,1]\n\t" \
        "v_pk_fma_f32 %7, %11, %12, %7 op_sel:[0,1,0] op_sel_hi:[1,1,1]" \
        : "+v"(acc[0][0]), "+v"(acc[0][1]), "+v"(acc[1][0]), "+v"(acc[1][1]), \
          "+v"(acc[2][0]), "+v"(acc[2][1]), "+v"(acc[3][0]), "+v"(acc[3][1]) \
        : "v"(Q0), "v"(Q1), "v"(Q2), "v"(Q3), "v"(WV))

__global__ __launch_bounds__(WGT, 4)
void dsnn_kernel(const float* __restrict__ x,
                 const float* __restrict__ W0,
                 const float* __restrict__ W1,
                 const float* __restrict__ W2,
                 float* __restrict__ out)
{
    __shared__ __align__(16) float spkbuf[256 * CPAD];  // 36864 B; x-stage f32, then fp8 spikes
    __shared__ __align__(16) float h0buf[ROWS * HPAD];  // 66048 B, [row][col]
    uint8_t* spk8 = (uint8_t*)spkbuf;                   // fp8 spike view: [col][row byte], stride SPB

    const int t  = threadIdx.x;
    const int c2 = (t & 255) * 2;          // cols c2, c2+1
    const int g  = (t >> 8) * 8;           // rows g..g+7 (wave-uniform)
    const int r0 = blockIdx.x * ROWS;

    // ---- stage x (pos/neg split) into spkbuf [i][row], i = 0..255 ----
    for (int k = t; k < 256 * ROWS; k += WGT) {
        const int i = k >> 5;
        const int r = k & 31;
        const float v = (i < 128) ? x[(size_t)(r0 + r) * 128 + i]
                                  : -x[(size_t)(r0 + r) * 128 + (i - 128)];
        spkbuf[i * CPAD + r] = fmaxf(v, 0.0f);
    }
    __syncthreads();

    f32x2 acc[4][2];   // [row-pair p][col cc]: rows 2p,2p+1 of col c2+cc

    // ---- h0 gemm (f32 x-values, runs once; row-pair col-broadcast pk_fma) ----
    auto gemm_x = [&](const float* Wbase, int K) {
        #pragma unroll 2
        for (int j = 0; j < K; ++j) {
            const float* sb = spkbuf + j * CPAD + g;       // wave-uniform -> broadcast
            const f32x4 sA = *(const f32x4*)(sb);
            const f32x4 sB = *(const f32x4*)(sb + 4);
            const f32x2 wv = *(const f32x2*)(Wbase + (size_t)j * 512 + c2);
            f32x2 q0 = { sA[0], sA[1] };   // rows g+0,g+1 (contiguous sub-pairs, no movs)
            f32x2 q1 = { sA[2], sA[3] };   // rows g+2,g+3
            f32x2 q2 = { sB[0], sB[1] };   // rows g+4,g+5
            f32x2 q3 = { sB[2], sB[3] };   // rows g+6,g+7
            PKCOL8(q0, q1, q2, q3, wv);
        }
    };

    // ---- fp8-spike gemm: 1 ds_read_b64 (8 rows) -> 4 pair-native cvt_pk
    //      (builtin) + 8 col-broadcast pk_fma. ----
    auto gemm_h = [&](const float* Wbase, int K) {
        #pragma unroll 8
        for (int j = 0; j < K; ++j) {
            const uint2 sp = *(const uint2*)(spk8 + j * SPB + g);
            const f32x2 wv = *(const f32x2*)(Wbase + (size_t)j * 512 + c2);
            f32x2 q0 = __builtin_amdgcn_cvt_pk_f32_fp8(sp.x, false);  // rows g+0,g+1
            f32x2 q1 = __builtin_amdgcn_cvt_pk_f32_fp8(sp.x, true);   // rows g+2,g+3
            f32x2 q2 = __builtin_amdgcn_cvt_pk_f32_fp8(sp.y, false);  // rows g+4,g+5
            f32x2 q3 = __builtin_amdgcn_cvt_pk_f32_fp8(sp.y, true);   // rows g+6,g+7
            PKCOL8(q0, q1, q2, q3, wv);
        }
    };

    // ---- h0 = x @ W0 (time-invariant), park in LDS ----
    #pragma unroll
    for (int p = 0; p < 4; ++p) { acc[p][0] = (f32x2){0.f,0.f}; acc[p][1] = (f32x2){0.f,0.f}; }
    gemm_x(W0, 256);
    #pragma unroll
    for (int r = 0; r < 8; ++r) {
        f32x2 hv = { acc[r >> 1][0][r & 1], acc[r >> 1][1][r & 1] };
        *(f32x2*)(h0buf + (g + r) * HPAD + c2) = hv;
    }
    __syncthreads();   // all x-reads done before spkbuf is reused for fp8 spikes

    // ---- recurrent state in registers/AGPRs: 5 x 16 = 80 ----
    float m0[8][2], s1[8][2], m1[8][2], s2[8][2], m2[8][2];
    #pragma unroll
    for (int r = 0; r < 8; ++r)
        #pragma unroll
        for (int cc = 0; cc < 2; ++cc) {
            m0[r][cc] = 0.f; s1[r][cc] = 0.f; m1[r][cc] = 0.f;
            s2[r][cc] = 0.f; m2[r][cc] = 0.f;
        }

    for (int step = 0; step < NSTEPS; ++step) {
        // ===== layer 0: m0 = BETA*m0 + h0; spike; reset; fp8 spikes -> LDS =====
        {
            bool bA[2][4], bB[2][4];   // [cc][rr]: rows g+rr / g+4+rr
            #pragma unroll
            for (int rr = 0; rr < 4; ++rr) {
                const f32x2 hva = *(const f32x2*)(h0buf + (g + rr) * HPAD + c2);
                const f32x2 hvb = *(const f32x2*)(h0buf + (g + 4 + rr) * HPAD + c2);
                LIF_L0(m0[rr][0], hva.x, bA[0][rr]);
                LIF_L0(m0[rr][1], hva.y, bA[1][rr]);
                LIF_L0(m0[4 + rr][0], hvb.x, bB[0][rr]);
                LIF_L0(m0[4 + rr][1], hvb.y, bB[1][rr]);
            }
            #pragma unroll
            for (int cc = 0; cc < 2; ++cc) {
                uint2 pk;
                pk.x = PK4B(bA[cc][0], bA[cc][1], bA[cc][2], bA[cc][3]);  // rows g..g+3
                pk.y = PK4B(bB[cc][0], bB[cc][1], bB[cc][2], bB[cc][3]);  // rows g+4..g+7
                *(uint2*)(spk8 + (c2 + cc) * SPB + g) = pk;
            }
        }
        __syncthreads();                       // A: L0 spikes visible

        // ===== layer 1: h1 = spk0 @ W1 =====
        #pragma unroll
        for (int p = 0; p < 4; ++p) { acc[p][0] = (f32x2){0.f,0.f}; acc[p][1] = (f32x2){0.f,0.f}; }
        gemm_h(W1, 512);
        __syncthreads();                       // B: all reads of L0 spikes done

        {
            bool bA[2][4], bB[2][4];
            #pragma unroll
            for (int rr = 0; rr < 4; ++rr) {
                LIF_MID(s1[rr][0], m1[rr][0], acc[rr >> 1][0][rr & 1], bA[0][rr]);
                LIF_MID(s1[rr][1], m1[rr][1], acc[rr >> 1][1][rr & 1], bA[1][rr]);
                LIF_MID(s1[4 + rr][0], m1[4 + rr][0], acc[(4 + rr) >> 1][0][rr & 1], bB[0][rr]);
                LIF_MID(s1[4 + rr][1], m1[4 + rr][1], acc[(4 + rr) >> 1][1][rr & 1], bB[1][rr]);
            }
            #pragma unroll
            for (int cc = 0; cc < 2; ++cc) {
                uint2 pk;
                pk.x = PK4B(bA[cc][0], bA[cc][1], bA[cc][2], bA[cc][3]);
                pk.y = PK4B(bB[cc][0], bB[cc][1], bB[cc][2], bB[cc][3]);
                *(uint2*)(spk8 + (c2 + cc) * SPB + g) = pk;
            }
        }
        __syncthreads();                       // C: L1 spikes visible

        // ===== layer 2: h2 = spk1 @ W2; s2,m2 update; no reset =====
        #pragma unroll
        for (int p = 0; p < 4; ++p) { acc[p][0] = (f32x2){0.f,0.f}; acc[p][1] = (f32x2){0.f,0.f}; }
        gemm_h(W2, 512);
        #pragma unroll
        for (int r = 0; r < 8; ++r) {
            LIF_OUT(s2[r][0], m2[r][0], acc[r >> 1][0][r & 1]);
            LIF_OUT(s2[r][1], m2[r][1], acc[r >> 1][1][r & 1]);
        }
        __syncthreads();                       // D: L1-spike reads done before next L0 write
    }

    // ---- write final m2 ----
    #pragma unroll
    for (int r = 0; r < 8; ++r) {
        f32x2 ov = { m2[r][0], m2[r][1] };
        *(f32x2*)(out + (size_t)(r0 + g + r) * 512 + c2) = ov;
    }
}

extern "C" void kernel_launch(void* const* d_in, const int* in_sizes, int n_in,
                              void* d_out, int out_size, void* d_ws, size_t ws_size,
                              hipStream_t stream) {
    const float* inputs = (const float*)d_in[0];   // 16384 x 128
    const float* W0     = (const float*)d_in[1];   // 256 x 512
    const float* W1     = (const float*)d_in[2];   // 512 x 512
    const float* W2     = (const float*)d_in[3];   // 512 x 512
    float* out          = (float*)d_out;           // 16384 x 512

    dim3 grid(16384 / ROWS);     // 512 workgroups, 32 rows each
    dim3 block(WGT);
    dsnn_kernel<<<grid, block, 0, stream>>>(inputs, W0, W1, W2, out);
}

// Round 18
// 30871.918 us; speedup vs baseline: 1.3074x; 1.3074x over previous
//
#include <hip/hip_runtime.h>
#include <stdint.h>

// DSNN bit-exact fp32. Locked-in facts:
//  - Ref is k-ascending single-accumulator fma (absmax 0.0 through R14); any
//    reorder/reprecision flips spikes chaotically. No MFMA (no fp32 MFMA).
//  - Floor evidence (16 waves/CU, r=8 c=2):
//      R7  (2xb128 f32 spikes, 16 fmaf):  LDS 320, VALU 225 -> wall 304
//      R10 (2xb128 f32 spikes, 8 pk_fma): LDS 320, VALU 149 -> wall 305
//      R14 (1xb64 fp8 + cvt_pk):          LDS  96, VALU 225+cvt -> wall 372
//    -> wall tracks per-CU LDS ISSUE (16 waves x 2 b128 x ~10cyc); VALU cuts
//    don't help, byte cuts that add VALU hurt. SMEM line (R17-R24): compile
//    fix + 1 core-dump, 0 measurements -> abandoned.
//  - R25 (this): halve LDS issue by RETILING, not repacking. 8 waves x
//    (8 rows x 4 cols)/thread, WGT=512: per CU-j LDS = 8x2 b128 = 160 cyc,
//    TCP unchanged (dwordx4 W, 8192B/CU-j = 128), VALU pipe = 2 waves/SIMD
//    x 16 pk_fma x 4cyc = 128. Same proven b128 broadcast + R14-proven
//    op_sel col-broadcast pk_fma (16/j from one W dwordx4) -> bit-exact.
//    Regs: state 5x8x4=160 + acc 32 + temps ~215 < 256 @ 2 waves/SIMD.
//    Model: max(160,128,128)+sync -> predict ~21-25 ms (from 33.0).

typedef __attribute__((ext_vector_type(2))) float f32x2;
typedef __attribute__((ext_vector_type(4))) float f32x4;

#define ALPHA 0.9f
#define BETA 0.85f
#define NSTEPS 127
#define WGT 512
#define ROWS 32
#define CPAD 36     // spkbuf col stride (floats): 32 rows + 4 pad
#define HPAD 516    // h0buf row stride (floats)

// Update forms verbatim (bit-exact-verified vs np reference).
#define LIF_L0(M, H, SP) { float _m = BETA * (M) + (H); \
    const bool _b = (_m - 1.0f) > 0.0f; (M) = _b ? 0.0f : _m; \
    (SP) = _b ? 1.0f : 0.0f; }
#define LIF_MID(S, M, A, SP) { (S) = ALPHA * (S) + (A); \
    float _m = BETA * (M) + (S); const bool _b = (_m - 1.0f) > 0.0f; \
    (M) = _b ? 0.0f : _m; (SP) = _b ? 1.0f : 0.0f; }
#define LIF_OUT(S, M, A) { (S) = ALPHA * (S) + (A); (M) = BETA * (M) + (S); }

// Row-pair col-broadcast pk_fma (R14-proven op_sel mapping, absmax 0.0):
// acc[p][c] = f32x2 over rows (2p,2p+1) of col c. src0 = spike row-pair,
// src1 = W col-pair with one col broadcast to both halves:
//   col-lo: op_sel:[0,0,0] op_sel_hi:[1,0,1]
//   col-hi: op_sel:[0,1,0] op_sel_hi:[1,1,1]
// 16 pk_fma: 4 row-pairs x 4 cols (2 W pairs). Each half is an independent
// IEEE f32 fma -> bit-exact chain per (row,col).
#define PK16(Q0, Q1, Q2, Q3, W01, W23) \
    asm("v_pk_fma_f32 %0, %16, %20, %0 op_sel:[0,0,0] op_sel_hi:[1,0,1]\n\t" \
        "v_pk_fma_f32 %1, %16, %20, %1 op_sel:[0,1,0] op_sel_hi:[1,1,1]\n\t" \
        "v_pk_fma_f32 %2, %16, %21, %2 op_sel:[0,0,0] op_sel_hi:[1,0,1]\n\t" \
        "v_pk_fma_f32 %3, %16, %21, %3 op_sel:[0,1,0] op_sel_hi:[1,1,1]\n\t" \
        "v_pk_fma_f32 %4, %17, %20, %4 op_sel:[0,0,0] op_sel_hi:[1,0,1]\n\t" \
        "v_pk_fma_f32 %5, %17, %20, %5 op_sel:[0,1,0] op_sel_hi:[1,1,1]\n\t" \
        "v_pk_fma_f32 %6, %17, %21, %6 op_sel:[0,0,0] op_sel_hi:[1,0,1]\n\t" \
        "v_pk_fma_f32 %7, %17, %21, %7 op_sel:[0,1,0] op_sel_hi:[1,1,1]\n\t" \
        "v_pk_fma_f32 %8, %18, %20, %8 op_sel:[0,0,0] op_sel_hi:[1,0,1]\n\t" \
        "v_pk_fma_f32 %9, %18, %20, %9 op_sel:[0,1,0] op_sel_hi:[1,1,1]\n\t" \
        "v_pk_fma_f32 %10, %18, %21, %10 op_sel:[0,0,0] op_sel_hi:[1,0,1]\n\t" \
        "v_pk_fma_f32 %11, %18, %21, %11 op_sel:[0,1,0] op_sel_hi:[1,1,1]\n\t" \
        "v_pk_fma_f32 %12, %19, %20, %12 op_sel:[0,0,0] op_sel_hi:[1,0,1]\n\t" \
        "v_pk_fma_f32 %13, %19, %20, %13 op_sel:[0,1,0] op_sel_hi:[1,1,1]\n\t" \
        "v_pk_fma_f32 %14, %19, %21, %14 op_sel:[0,0,0] op_sel_hi:[1,0,1]\n\t" \
        "v_pk_fma_f32 %15, %19, %21, %15 op_sel:[0,1,0] op_sel_hi:[1,1,1]" \
        : "+v"(acc[0][0]), "+v"(acc[0][1]), "+v"(acc[0][2]), "+v"(acc[0][3]), \
          "+v"(acc[1][0]), "+v"(acc[1][1]), "+v"(acc[1][2]), "+v"(acc[1][3]), \
          "+v"(acc[2][0]), "+v"(acc[2][1]), "+v"(acc[2][2]), "+v"(acc[2][3]), \
          "+v"(acc[3][0]), "+v"(acc[3][1]), "+v"(acc[3][2]), "+v"(acc[3][3]) \
        : "v"(Q0), "v"(Q1), "v"(Q2), "v"(Q3), "v"(W01), "v"(W23))

__global__ __launch_bounds__(WGT, 2)
void dsnn_kernel(const float* __restrict__ x,
                 const float* __restrict__ W0,
                 const float* __restrict__ W1,
                 const float* __restrict__ W2,
                 float* __restrict__ out)
{
    __shared__ float spkbuf[512 * CPAD];   // 73728 B, [index][row] (x-stage, then spikes)
    __shared__ float h0buf[ROWS * HPAD];   // 66048 B, [row][col]

    const int t  = threadIdx.x;
    const int c4 = (t & 127) * 4;          // cols c4..c4+3
    const int g  = (t >> 7) * 8;           // rows g..g+7 (wave-uniform: 128-thread groups)
    const int r0 = blockIdx.x * ROWS;

    // ---- stage x (pos/neg split) into spkbuf [i][row], i = 0..255 ----
    for (int k = t; k < 256 * ROWS; k += WGT) {
        const int i = k >> 5;
        const int r = k & 31;
        const float v = (i < 128) ? x[(size_t)(r0 + r) * 128 + i]
                                  : -x[(size_t)(r0 + r) * 128 + (i - 128)];
        spkbuf[i * CPAD + r] = fmaxf(v, 0.0f);
    }
    __syncthreads();

    f32x2 acc[4][4];   // [row-pair p][col cc]: rows 2p,2p+1 of col c4+cc

    // acc[p][cc] += buf[j][g+2p+(0,1)] * W[j][c4+cc], j ascending (bit-exact).
    // 2 b128 spike broadcasts + 1 dwordx4 W load + 16 pk_fma per j.
    auto gemm = [&](const float* Wbase, int K) {
        #pragma unroll 2
        for (int j = 0; j < K; ++j) {
            const float* sb = spkbuf + j * CPAD + g;       // wave-uniform -> broadcast
            const f32x4 sA = *(const f32x4*)(sb);          // rows g..g+3
            const f32x4 sB = *(const f32x4*)(sb + 4);      // rows g+4..g+7
            const f32x4 wv = *(const f32x4*)(Wbase + (size_t)j * 512 + c4);
            f32x2 q0 = { sA[0], sA[1] };   // contiguous sub-pairs (no movs)
            f32x2 q1 = { sA[2], sA[3] };
            f32x2 q2 = { sB[0], sB[1] };
            f32x2 q3 = { sB[2], sB[3] };
            f32x2 w01 = { wv[0], wv[1] };
            f32x2 w23 = { wv[2], wv[3] };
            PK16(q0, q1, q2, q3, w01, w23);
        }
    };

    // ---- h0 = x @ W0 (time-invariant), park in LDS ----
    #pragma unroll
    for (int p = 0; p < 4; ++p)
        #pragma unroll
        for (int cc = 0; cc < 4; ++cc) acc[p][cc] = (f32x2){0.f, 0.f};
    gemm(W0, 256);
    #pragma unroll
    for (int r = 0; r < 8; ++r) {
        f32x4 hv = { acc[r >> 1][0][r & 1], acc[r >> 1][1][r & 1],
                     acc[r >> 1][2][r & 1], acc[r >> 1][3][r & 1] };
        *(f32x4*)(h0buf + (g + r) * HPAD + c4) = hv;
    }
    __syncthreads();   // all x-reads done before spkbuf is reused for spikes

    // ---- recurrent state in registers: 5 x 8 x 4 = 160 ----
    float m0[8][4], s1[8][4], m1[8][4], s2[8][4], m2[8][4];
    #pragma unroll
    for (int r = 0; r < 8; ++r)
        #pragma unroll
        for (int cc = 0; cc < 4; ++cc) {
            m0[r][cc] = 0.f; s1[r][cc] = 0.f; m1[r][cc] = 0.f;
            s2[r][cc] = 0.f; m2[r][cc] = 0.f;
        }

    for (int step = 0; step < NSTEPS; ++step) {
        // ===== layer 0: m0 = BETA*m0 + h0; spike; reset; spikes -> spkbuf =====
        {
            f32x4 svA[4], svB[4];   // [cc] rows g..g+3 / g+4..g+7
            #pragma unroll
            for (int rr = 0; rr < 4; ++rr) {
                const f32x4 hva = *(const f32x4*)(h0buf + (g + rr) * HPAD + c4);
                const f32x4 hvb = *(const f32x4*)(h0buf + (g + 4 + rr) * HPAD + c4);
                #pragma unroll
                for (int cc = 0; cc < 4; ++cc) {
                    LIF_L0(m0[rr][cc], hva[cc], svA[cc][rr]);
                    LIF_L0(m0[4 + rr][cc], hvb[cc], svB[cc][rr]);
                }
            }
            #pragma unroll
            for (int cc = 0; cc < 4; ++cc) {
                *(f32x4*)(spkbuf + (c4 + cc) * CPAD + g)     = svA[cc];
                *(f32x4*)(spkbuf + (c4 + cc) * CPAD + g + 4) = svB[cc];
            }
        }
        __syncthreads();                       // A: L0 spikes visible

        // ===== layer 1: h1 = spk0 @ W1 =====
        #pragma unroll
        for (int p = 0; p < 4; ++p)
            #pragma unroll
            for (int cc = 0; cc < 4; ++cc) acc[p][cc] = (f32x2){0.f, 0.f};
        gemm(W1, 512);
        __syncthreads();                       // B: all reads of L0 spikes done

        {
            f32x4 svA[4], svB[4];
            #pragma unroll
            for (int rr = 0; rr < 4; ++rr) {
                #pragma unroll
                for (int cc = 0; cc < 4; ++cc) {
                    LIF_MID(s1[rr][cc], m1[rr][cc],
                            acc[rr >> 1][cc][rr & 1], svA[cc][rr]);
                    LIF_MID(s1[4 + rr][cc], m1[4 + rr][cc],
                            acc[(4 + rr) >> 1][cc][rr & 1], svB[cc][rr]);
                }
            }
            #pragma unroll
            for (int cc = 0; cc < 4; ++cc) {
                *(f32x4*)(spkbuf + (c4 + cc) * CPAD + g)     = svA[cc];
                *(f32x4*)(spkbuf + (c4 + cc) * CPAD + g + 4) = svB[cc];
            }
        }
        __syncthreads();                       // C: L1 spikes visible

        // ===== layer 2: h2 = spk1 @ W2; s2,m2 update; no reset =====
        #pragma unroll
        for (int p = 0; p < 4; ++p)
            #pragma unroll
            for (int cc = 0; cc < 4; ++cc) acc[p][cc] = (f32x2){0.f, 0.f};
        gemm(W2, 512);
        #pragma unroll
        for (int r = 0; r < 8; ++r)
            #pragma unroll
            for (int cc = 0; cc < 4; ++cc)
                LIF_OUT(s2[r][cc], m2[r][cc], acc[r >> 1][cc][r & 1]);
        __syncthreads();                       // D: L1-spike reads done before next L0 write
    }

    // ---- write final m2 ----
    #pragma unroll
    for (int r = 0; r < 8; ++r) {
        f32x4 ov = { m2[r][0], m2[r][1], m2[r][2], m2[r][3] };
        *(f32x4*)(out + (size_t)(r0 + g + r) * 512 + c4) = ov;
    }
}

extern "C" void kernel_launch(void* const* d_in, const int* in_sizes, int n_in,
                              void* d_out, int out_size, void* d_ws, size_t ws_size,
                              hipStream_t stream) {
    const float* inputs = (const float*)d_in[0];   // 16384 x 128
    const float* W0     = (const float*)d_in[1];   // 256 x 512
    const float* W1     = (const float*)d_in[2];   // 512 x 512
    const float* W2     = (const float*)d_in[3];   // 512 x 512
    float* out          = (float*)d_out;           // 16384 x 512

    dim3 grid(16384 / ROWS);     // 512 workgroups, 32 rows each
    dim3 block(WGT);             // 8 waves: 4 row-groups x (128 threads x 4 cols)
    dsnn_kernel<<<grid, block, 0, stream>>>(inputs, W0, W1, W2, out);
}